// Round 12
// baseline (2998.009 us; speedup 1.0000x reference)
//
#include <hip/hip_runtime.h>
#include <hip/hip_bf16.h>

#define B_   64
#define T_   2048
#define IN_  256
#define H_   128
#define G_   512          // 4*H
#define M_   (B_ * T_)    // 131072

typedef __bf16 bf16x8 __attribute__((ext_vector_type(8)));
typedef _Float16 f16x8 __attribute__((ext_vector_type(8)));
typedef float f32x4 __attribute__((ext_vector_type(4)));
typedef unsigned short u16x8 __attribute__((ext_vector_type(8)));

#define L2E_  1.442695041f

__device__ __forceinline__ unsigned short f2bf(float f) {   // RNE fp32->bf16
    unsigned u = __float_as_uint(f);
    return (unsigned short)((u + 0x7fffu + ((u >> 16) & 1u)) >> 16);
}
__device__ __forceinline__ float sigp(float x) {
    return __builtin_amdgcn_rcpf(1.f + __builtin_amdgcn_exp2f(-L2E_ * x));
}
__device__ __forceinline__ float tanhp(float x) {
    return fmaf(2.f, __builtin_amdgcn_rcpf(1.f + __builtin_amdgcn_exp2f(-2.f * L2E_ * x)), -1.f);
}

// ---------------------------------------------------------------------------
// K1: bf16 MFMA GEMM.  xp[dir][m][q*4+g] = x[m].w_ih[dir][g*128+q] + biases
// ---------------------------------------------------------------------------
__global__ __launch_bounds__(256) void gemm_in_mfma(
    const float* __restrict__ x,
    const float* __restrict__ w_f, const float* __restrict__ w_b,
    const float* __restrict__ bi_f, const float* __restrict__ bh_f,
    const float* __restrict__ bi_b, const float* __restrict__ bh_b,
    __hip_bfloat16* __restrict__ xp)
{
    const int nt  = blockIdx.x;          // 0..15
    const int m0  = blockIdx.y * 64;
    const int dir = nt >> 3;
    const int q0  = (nt & 7) * 16;
    const float* __restrict__ w  = dir ? w_b  : w_f;
    const float* __restrict__ bi = dir ? bi_b : bi_f;
    const float* __restrict__ bh = dir ? bh_b : bh_f;

    __shared__ alignas(16) unsigned short Asm[64 * 64];
    __shared__ alignas(16) unsigned short Bsm[64 * 64];
    __shared__ float bias_s[64];

    const int tid = threadIdx.x;
    const int wv  = tid >> 6;
    const int ln  = tid & 63;
    const int wr  = (wv >> 1) * 32;
    const int wc  = (wv & 1) * 32;
    const int l15 = ln & 15;
    const int l4  = ln >> 4;

#define STAGE_A(c2, k0) { int row = (c2) >> 3, kc = (c2) & 7; \
    const float4* sp = reinterpret_cast<const float4*>(x + (size_t)(m0 + row) * 256 + (k0) + kc * 8); \
    float4 fa = sp[0], fb = sp[1]; \
    u16x8 pk; pk[0]=f2bf(fa.x); pk[1]=f2bf(fa.y); pk[2]=f2bf(fa.z); pk[3]=f2bf(fa.w); \
    pk[4]=f2bf(fb.x); pk[5]=f2bf(fb.y); pk[6]=f2bf(fb.z); pk[7]=f2bf(fb.w); \
    *reinterpret_cast<u16x8*>(reinterpret_cast<char*>(Asm) + row * 128 + ((kc * 16) ^ ((row & 7) << 4))) = pk; }

#define STAGE_B(c2, k0) { int row = (c2) >> 3, kc = (c2) & 7; \
    int nglob = (row & 3) * 128 + q0 + (row >> 2); \
    const float4* sp = reinterpret_cast<const float4*>(w + (size_t)nglob * 256 + (k0) + kc * 8); \
    float4 fa = sp[0], fb = sp[1]; \
    u16x8 pk; pk[0]=f2bf(fa.x); pk[1]=f2bf(fa.y); pk[2]=f2bf(fa.z); pk[3]=f2bf(fa.w); \
    pk[4]=f2bf(fb.x); pk[5]=f2bf(fb.y); pk[6]=f2bf(fb.z); pk[7]=f2bf(fb.w); \
    *reinterpret_cast<u16x8*>(reinterpret_cast<char*>(Bsm) + row * 128 + ((kc * 16) ^ ((row & 7) << 4))) = pk; }

#define FRAG(BASE, rowe, kb) \
    __builtin_bit_cast(bf16x8, *reinterpret_cast<const uint4*>( \
        reinterpret_cast<const char*>(BASE) + (rowe) * 128 + ((kb) ^ (((rowe) & 7) << 4))))

    STAGE_A(tid, 0)  STAGE_A(tid + 256, 0)
    STAGE_B(tid, 0)  STAGE_B(tid + 256, 0)
    if (tid < 64) {
        int n = (tid & 3) * 128 + q0 + (tid >> 2);
        bias_s[tid] = bi[n] + bh[n];
    }
    __syncthreads();

    const float bv0 = bias_s[wc + l15];
    const float bv1 = bias_s[wc + 16 + l15];
    f32x4 acc00 = {bv0, bv0, bv0, bv0};
    f32x4 acc01 = {bv1, bv1, bv1, bv1};
    f32x4 acc10 = {bv0, bv0, bv0, bv0};
    f32x4 acc11 = {bv1, bv1, bv1, bv1};

    const int ra0 = wr + l15,      ra1 = wr + 16 + l15;
    const int rb0 = wc + l15,      rb1 = wc + 16 + l15;

    for (int kst = 0; kst < 4; ++kst) {
        if (kst) {
            __syncthreads();
            STAGE_A(tid, kst * 64)  STAGE_A(tid + 256, kst * 64)
            STAGE_B(tid, kst * 64)  STAGE_B(tid + 256, kst * 64)
            __syncthreads();
        }
        #pragma unroll
        for (int ks = 0; ks < 64; ks += 32) {
            int kb = ks * 2 + (l4 << 4);
            bf16x8 a0 = FRAG(Asm, ra0, kb);
            bf16x8 a1 = FRAG(Asm, ra1, kb);
            bf16x8 b0 = FRAG(Bsm, rb0, kb);
            bf16x8 b1 = FRAG(Bsm, rb1, kb);
            acc00 = __builtin_amdgcn_mfma_f32_16x16x32_bf16(a0, b0, acc00, 0, 0, 0);
            acc01 = __builtin_amdgcn_mfma_f32_16x16x32_bf16(a0, b1, acc01, 0, 0, 0);
            acc10 = __builtin_amdgcn_mfma_f32_16x16x32_bf16(a1, b0, acc10, 0, 0, 0);
            acc11 = __builtin_amdgcn_mfma_f32_16x16x32_bf16(a1, b1, acc11, 0, 0, 0);
        }
    }
    __syncthreads();

#define DWRITE(accv, mi, ni) { int row = wr + (mi) * 16 + l4 * 4; int col = wc + (ni) * 16 + l15; \
    Asm[(row + 0) * 64 + col] = f2bf(accv[0]); Asm[(row + 1) * 64 + col] = f2bf(accv[1]); \
    Asm[(row + 2) * 64 + col] = f2bf(accv[2]); Asm[(row + 3) * 64 + col] = f2bf(accv[3]); }
    DWRITE(acc00, 0, 0) DWRITE(acc01, 0, 1) DWRITE(acc10, 1, 0) DWRITE(acc11, 1, 1)
#undef DWRITE
    __syncthreads();

    #pragma unroll
    for (int p = 0; p < 2; ++p) {
        int c2 = tid + p * 256;
        int row = c2 >> 3, ch = c2 & 7;
        uint4 v = *reinterpret_cast<const uint4*>(reinterpret_cast<const char*>(Asm) + row * 128 + ch * 16);
        *reinterpret_cast<uint4*>(xp + ((size_t)dir * M_ + m0 + row) * G_ + q0 * 4 + ch * 8) = v;
    }
#undef STAGE_A
#undef STAGE_B
}

// ---------------------------------------------------------------------------
// K2 v2: MULTI-CHAIN persistent recurrence on the MFMA pipe.
// 16 WGs x 1024 thr (16 waves); each WG = 8 chains of one direction.
// Wave w owns row-tiles {2w,2w+1} (rows 32w..32w+31 of W', r=Q*4+g order):
// A-frags = 8 x f16x8 = 32 VGPRs/lane (below the r5-r11 residency cliff; the
// weight stream is also amortized 8x if it ever remats).
// B operand = h for 8 chains in MFMA columns (cols 8-15 duplicate 0-7 ->
// duplicated lanes read the same LDS address = broadcast).
// D gives each lane all 4 gates of cell Q=8w+4ts+l4, chain l15&7, in regs
// 0..3; lanes l15<8 own ts=0, l15>=8 own ts=1 (branch-free select) ->
// every lane activates exactly one cell (10 trans/step) and writes a unique
// (chain, cell) h to LDS (fp16, 272-B chain stride for bank spread) + global.
// acc is initialized from 4-step-prefetched xp (input+bias). One lgkm-only
// raw barrier per step; HBM prefetches stay in flight.
// ---------------------------------------------------------------------------
__global__ __launch_bounds__(1024)
__attribute__((amdgpu_waves_per_eu(4, 4)))
void lstm_rec(
    const __hip_bfloat16* __restrict__ xp,   // [2][B][T][512] (r=Q*4+g)
    const float* __restrict__ w_hh_f,        // [G][H]
    const float* __restrict__ w_hh_b,
    __hip_bfloat16* __restrict__ hs)         // [B][T][2H]
{
    const int wg  = blockIdx.x;              // 0..15
    const int dir = wg >> 3;
    const int bb  = (wg & 7) * 8;            // chains bb..bb+7
    const int tid = threadIdx.x;
    const int w   = tid >> 6;                // wave 0..15
    const int l   = tid & 63;
    const int l15 = l & 15;
    const int l4  = l >> 4;
    const int ch  = l15 & 7;                 // chain column (dup for l15>=8)
    const bool primary = (l15 < 8);
    const float* __restrict__ w_hh = dir ? w_hh_b : w_hh_f;

    // ---- A fragments: W'[32w + 16*ts + l15][32*kt + 8*l4 + i] -------------
    // W' row r maps to w_hh row (r&3)*128 + (r>>2).
#define LDW(ts, kt) f16x8 W##ts##_##kt; { \
    int r = 32 * w + 16 * (ts) + l15; \
    const float* p = w_hh + (size_t)((r & 3) * 128 + (r >> 2)) * 128 + 32 * (kt) + 8 * l4; \
    float4 u0 = *reinterpret_cast<const float4*>(p); \
    float4 u1 = *reinterpret_cast<const float4*>(p + 4); \
    W##ts##_##kt[0] = (_Float16)u0.x; W##ts##_##kt[1] = (_Float16)u0.y; \
    W##ts##_##kt[2] = (_Float16)u0.z; W##ts##_##kt[3] = (_Float16)u0.w; \
    W##ts##_##kt[4] = (_Float16)u1.x; W##ts##_##kt[5] = (_Float16)u1.y; \
    W##ts##_##kt[6] = (_Float16)u1.z; W##ts##_##kt[7] = (_Float16)u1.w; }
    LDW(0,0) LDW(0,1) LDW(0,2) LDW(0,3)
    LDW(1,0) LDW(1,1) LDW(1,2) LDW(1,3)
#undef LDW

    // h double buffer: [2][chain][136 halfs] (272-B stride: 16B-aligned, bank-spread)
    __shared__ alignas(16) _Float16 hbuf[2][8][136];
    for (int i = tid; i < 2 * 8 * 136; i += 1024) (&hbuf[0][0][0])[i] = (_Float16)0.f;
    __syncthreads();

    const unsigned short* __restrict__ xb =
        reinterpret_cast<const unsigned short*>(xp) +
        ((size_t)(dir * B_ + bb + ch)) * T_ * G_;
    const int Qw = primary ? (8 * w + l4) : (8 * w + 4 + l4);   // owned cell
    __hip_bfloat16* __restrict__ ho =
        hs + (size_t)(bb + ch) * T_ * (2 * H_) + dir * H_;
    float cst = 0.f;
    int t = dir ? (T_ - 1) : 0;
    const int dt = dir ? -1 : 1;

    const int xoff0 = 32 * w + 4 * l4;        // ts=0 gate-row base
    const int xoff1 = 32 * w + 16 + 4 * l4;   // ts=1

#define XPLD(sp, off) (*reinterpret_cast<const uint2*>( \
    xb + (size_t)(dir ? (T_ - 1 - (sp)) : (sp)) * G_ + (off)))

    uint2 cA0 = XPLD(0, xoff0), cA1 = XPLD(0, xoff1);
    uint2 cB0 = XPLD(1, xoff0), cB1 = XPLD(1, xoff1);
    uint2 cC0 = XPLD(2, xoff0), cC1 = XPLD(2, xoff1);
    uint2 cD0 = XPLD(3, xoff0), cD1 = XPLD(3, xoff1);

#define LOF(u) __uint_as_float((u) << 16)
#define HIF(u) __uint_as_float((u) & 0xffff0000u)
#define MFMA16(A, B, C) __builtin_amdgcn_mfma_f32_16x16x32_f16(A, B, C, 0, 0, 0)

#define STEP(par, X0, X1) { \
    const char* hp_ = reinterpret_cast<const char*>(&hbuf[par][0][0]) + ch * 272 + l4 * 16; \
    f16x8 hb0 = *reinterpret_cast<const f16x8*>(hp_ + 0); \
    f16x8 hb1 = *reinterpret_cast<const f16x8*>(hp_ + 64); \
    f16x8 hb2 = *reinterpret_cast<const f16x8*>(hp_ + 128); \
    f16x8 hb3 = *reinterpret_cast<const f16x8*>(hp_ + 192); \
    f32x4 a0, a1; \
    a0[0] = LOF(X0.x); a0[1] = HIF(X0.x); a0[2] = LOF(X0.y); a0[3] = HIF(X0.y); \
    a1[0] = LOF(X1.x); a1[1] = HIF(X1.x); a1[2] = LOF(X1.y); a1[3] = HIF(X1.y); \
    a0 = MFMA16(W0_0, hb0, a0); a1 = MFMA16(W1_0, hb0, a1); \
    a0 = MFMA16(W0_1, hb1, a0); a1 = MFMA16(W1_1, hb1, a1); \
    a0 = MFMA16(W0_2, hb2, a0); a1 = MFMA16(W1_2, hb2, a1); \
    a0 = MFMA16(W0_3, hb3, a0); a1 = MFMA16(W1_3, hb3, a1); \
    float gi = primary ? a0[0] : a1[0]; \
    float gf = primary ? a0[1] : a1[1]; \
    float gg = primary ? a0[2] : a1[2]; \
    float go = primary ? a0[3] : a1[3]; \
    float si = sigp(gi), sf = sigp(gf); \
    float tg = tanhp(gg), so = sigp(go); \
    cst = fmaf(sf, cst, si * tg); \
    float h = so * tanhp(cst); \
    hbuf[(par) ^ 1][ch][Qw] = (_Float16)h; \
    ho[(size_t)t * (2 * H_) + Qw] = __float2bfloat16(h); \
    asm volatile("s_waitcnt lgkmcnt(0)" ::: "memory"); \
    __builtin_amdgcn_s_barrier(); \
    t += dt; }

    for (int blk = 0; blk < T_ / 4; ++blk) {
        int base = blk * 4 + 4;
        int s0 = base     > T_ - 1 ? T_ - 1 : base;
        int s1 = base + 1 > T_ - 1 ? T_ - 1 : base + 1;
        int s2 = base + 2 > T_ - 1 ? T_ - 1 : base + 2;
        int s3 = base + 3 > T_ - 1 ? T_ - 1 : base + 3;
        uint2 nA0 = XPLD(s0, xoff0), nA1 = XPLD(s0, xoff1);
        uint2 nB0 = XPLD(s1, xoff0), nB1 = XPLD(s1, xoff1);
        uint2 nC0 = XPLD(s2, xoff0), nC1 = XPLD(s2, xoff1);
        uint2 nD0 = XPLD(s3, xoff0), nD1 = XPLD(s3, xoff1);

        STEP(0, cA0, cA1)
        STEP(1, cB0, cB1)
        STEP(0, cC0, cC1)
        STEP(1, cD0, cD1)

        cA0 = nA0; cA1 = nA1; cB0 = nB0; cB1 = nB1;
        cC0 = nC0; cC1 = nC1; cD0 = nD0; cD1 = nD1;
    }
#undef STEP
#undef MFMA16
#undef LOF
#undef HIF
#undef XPLD
}

// ---------------------------------------------------------------------------
// K3: bf16 MFMA mixer. out[m][n] = hs[m].mixer_w[n] + mb[n], fp32 out.
// ---------------------------------------------------------------------------
__global__ __launch_bounds__(256) void mixer_mfma(
    const __hip_bfloat16* __restrict__ hs,   // [M][256] bf16
    const float* __restrict__ mw,            // [256][256] fp32
    const float* __restrict__ mb,
    float* __restrict__ out)                 // [M][256] fp32
{
    const int n0 = blockIdx.x * 64;
    const int m0 = blockIdx.y * 64;

    __shared__ alignas(16) unsigned short Asm[64 * 64];
    __shared__ alignas(16) unsigned short Bsm[64 * 64];
    __shared__ alignas(16) float Dlds[64 * 64];
    __shared__ float bias_s[64];

    const int tid = threadIdx.x;
    const int wv  = tid >> 6;
    const int ln  = tid & 63;
    const int wr  = (wv >> 1) * 32;
    const int wc  = (wv & 1) * 32;
    const int l15 = ln & 15;
    const int l4  = ln >> 4;

#define STAGE_A3(c2, k0) { int row = (c2) >> 3, kc = (c2) & 7; \
    uint4 v = *reinterpret_cast<const uint4*>(hs + (size_t)(m0 + row) * 256 + (k0) + kc * 8); \
    *reinterpret_cast<uint4*>(reinterpret_cast<char*>(Asm) + row * 128 + ((kc * 16) ^ ((row & 7) << 4))) = v; }
#define STAGE_B3(c2, k0) { int row = (c2) >> 3, kc = (c2) & 7; \
    const float4* sp = reinterpret_cast<const float4*>(mw + (size_t)(n0 + row) * 256 + (k0) + kc * 8); \
    float4 fa = sp[0], fb = sp[1]; \
    u16x8 pk; pk[0]=f2bf(fa.x); pk[1]=f2bf(fa.y); pk[2]=f2bf(fa.z); pk[3]=f2bf(fa.w); \
    pk[4]=f2bf(fb.x); pk[5]=f2bf(fb.y); pk[6]=f2bf(fb.z); pk[7]=f2bf(fb.w); \
    *reinterpret_cast<u16x8*>(reinterpret_cast<char*>(Bsm) + row * 128 + ((kc * 16) ^ ((row & 7) << 4))) = pk; }

#define FRAG(BASE, rowe, kb) \
    __builtin_bit_cast(bf16x8, *reinterpret_cast<const uint4*>( \
        reinterpret_cast<const char*>(BASE) + (rowe) * 128 + ((kb) ^ (((rowe) & 7) << 4))))

    STAGE_A3(tid, 0)  STAGE_A3(tid + 256, 0)
    STAGE_B3(tid, 0)  STAGE_B3(tid + 256, 0)
    if (tid < 64) bias_s[tid] = mb[n0 + tid];
    __syncthreads();

    const float bv0 = bias_s[wc + l15];
    const float bv1 = bias_s[wc + 16 + l15];
    f32x4 acc00 = {bv0, bv0, bv0, bv0};
    f32x4 acc01 = {bv1, bv1, bv1, bv1};
    f32x4 acc10 = {bv0, bv0, bv0, bv0};
    f32x4 acc11 = {bv1, bv1, bv1, bv1};

    const int ra0 = wr + l15,      ra1 = wr + 16 + l15;
    const int rb0 = wc + l15,      rb1 = wc + 16 + l15;

    for (int kst = 0; kst < 4; ++kst) {
        if (kst) {
            __syncthreads();
            STAGE_A3(tid, kst * 64)  STAGE_A3(tid + 256, kst * 64)
            STAGE_B3(tid, kst * 64)  STAGE_B3(tid + 256, kst * 64)
            __syncthreads();
        }
        #pragma unroll
        for (int ks = 0; ks < 64; ks += 32) {
            int kb = ks * 2 + (l4 << 4);
            bf16x8 a0 = FRAG(Asm, ra0, kb);
            bf16x8 a1 = FRAG(Asm, ra1, kb);
            bf16x8 b0 = FRAG(Bsm, rb0, kb);
            bf16x8 b1 = FRAG(Bsm, rb1, kb);
            acc00 = __builtin_amdgcn_mfma_f32_16x16x32_bf16(a0, b0, acc00, 0, 0, 0);
            acc01 = __builtin_amdgcn_mfma_f32_16x16x32_bf16(a0, b1, acc01, 0, 0, 0);
            acc10 = __builtin_amdgcn_mfma_f32_16x16x32_bf16(a1, b0, acc10, 0, 0, 0);
            acc11 = __builtin_amdgcn_mfma_f32_16x16x32_bf16(a1, b1, acc11, 0, 0, 0);
        }
    }
    __syncthreads();

#define DWRITE3(accv, mi, ni) { int row = wr + (mi) * 16 + l4 * 4; int col = wc + (ni) * 16 + l15; \
    Dlds[(row + 0) * 64 + col] = accv[0]; Dlds[(row + 1) * 64 + col] = accv[1]; \
    Dlds[(row + 2) * 64 + col] = accv[2]; Dlds[(row + 3) * 64 + col] = accv[3]; }
    DWRITE3(acc00, 0, 0) DWRITE3(acc01, 0, 1) DWRITE3(acc10, 1, 0) DWRITE3(acc11, 1, 1)
#undef DWRITE3
    __syncthreads();

    #pragma unroll
    for (int p = 0; p < 4; ++p) {
        int c2 = tid + p * 256;
        int row = c2 >> 4, ch = c2 & 15;
        float4 v = *reinterpret_cast<const float4*>(Dlds + row * 64 + ch * 4);
        *reinterpret_cast<float4*>(out + (size_t)(m0 + row) * 256 + n0 + ch * 4) = v;
    }
#undef STAGE_A3
#undef STAGE_B3
#undef FRAG
}

// ---------------------------------------------------------------------------
extern "C" void kernel_launch(void* const* d_in, const int* in_sizes, int n_in,
                              void* d_out, int out_size, void* d_ws, size_t ws_size,
                              hipStream_t stream) {
    const float* x       = (const float*)d_in[0];
    const float* w_ih_f  = (const float*)d_in[1];
    const float* w_hh_f  = (const float*)d_in[2];
    const float* b_ih_f  = (const float*)d_in[3];
    const float* b_hh_f  = (const float*)d_in[4];
    const float* w_ih_b  = (const float*)d_in[5];
    const float* w_hh_b  = (const float*)d_in[6];
    const float* b_ih_b  = (const float*)d_in[7];
    const float* b_hh_b  = (const float*)d_in[8];
    const float* mixer_w = (const float*)d_in[9];
    const float* mixer_b = (const float*)d_in[10];
    float* out = (float*)d_out;

    const size_t xp_bytes = (size_t)2 * M_ * G_ * sizeof(__hip_bfloat16); // 256 MiB
    const size_t hs_bytes = (size_t)M_ * 2 * H_ * sizeof(__hip_bfloat16); //  64 MiB
    if (ws_size < xp_bytes + hs_bytes) return;

    __hip_bfloat16* xp = (__hip_bfloat16*)d_ws;
    __hip_bfloat16* hs = (__hip_bfloat16*)((char*)d_ws + xp_bytes);

    gemm_in_mfma<<<dim3(16, M_ / 64), 256, 0, stream>>>(
        x, w_ih_f, w_ih_b, b_ih_f, b_hh_f, b_ih_b, b_hh_b, xp);
    lstm_rec<<<16, 1024, 0, stream>>>(xp, w_hh_f, w_hh_b, hs);
    mixer_mfma<<<dim3(4, M_ / 64), 256, 0, stream>>>(
        hs, mixer_w, mixer_b, out);
}

// Round 13
// 1980.887 us; speedup vs baseline: 1.5135x; 1.5135x over previous
//
#include <hip/hip_runtime.h>
#include <hip/hip_bf16.h>

#define B_   64
#define T_   2048
#define IN_  256
#define H_   128
#define G_   512          // 4*H
#define M_   (B_ * T_)    // 131072

typedef __bf16 bf16x8 __attribute__((ext_vector_type(8)));
typedef _Float16 half2v __attribute__((ext_vector_type(2)));
typedef float f32x4 __attribute__((ext_vector_type(4)));
typedef unsigned short u16x8 __attribute__((ext_vector_type(8)));

#define L2E_  1.442695041f

__device__ __forceinline__ unsigned short f2bf(float f) {   // RNE fp32->bf16
    unsigned u = __float_as_uint(f);
    return (unsigned short)((u + 0x7fffu + ((u >> 16) & 1u)) >> 16);
}
__device__ __forceinline__ float dot2f(half2v a, half2v b, float c) {
    return __builtin_amdgcn_fdot2(a, b, c, false);
}
__device__ __forceinline__ half2v h2(unsigned int u) {
    return __builtin_bit_cast(half2v, u);
}
__device__ __forceinline__ float dpp_xor1(float x) {
    int i = __float_as_int(x);
    return __int_as_float(__builtin_amdgcn_update_dpp(i, i, 0xB1, 0xF, 0xF, true));
}
__device__ __forceinline__ float dpp_xor2(float x) {
    int i = __float_as_int(x);
    return __int_as_float(__builtin_amdgcn_update_dpp(i, i, 0x4E, 0xF, 0xF, true));
}
__device__ __forceinline__ float dpp_xor7(float x) {        // ROW_HALF_MIRROR
    int i = __float_as_int(x);
    return __int_as_float(__builtin_amdgcn_update_dpp(i, i, 0x141, 0xF, 0xF, true));
}
__device__ __forceinline__ float sigp(float x) {
    return __builtin_amdgcn_rcpf(1.f + __builtin_amdgcn_exp2f(-L2E_ * x));
}
__device__ __forceinline__ float tanhp(float x) {
    return fmaf(2.f, __builtin_amdgcn_rcpf(1.f + __builtin_amdgcn_exp2f(-2.f * L2E_ * x)), -1.f);
}

// ---------------------------------------------------------------------------
// K0: convert w_hh (fp32) -> wp (fp16) in K2's per-lane order:
// wp[((dir*1024 + Q*8+s)*4 + g)*16 + k] = w_hh[dir][g*128+Q][s*16+k]
// Each K2 lane then loads 64 contiguous fp16 (128 B) = 8 x dwordx4.
// ---------------------------------------------------------------------------
__global__ __launch_bounds__(256) void conv_whh(
    const float* __restrict__ wf, const float* __restrict__ wb,
    _Float16* __restrict__ wp)
{
    int idx = blockIdx.x * 256 + threadIdx.x;   // 0..8191 = (dir,Q,s,g)
    int g   = idx & 3;
    int Qs  = (idx >> 2) & 1023;
    int dir = idx >> 12;
    int Q = Qs >> 3, s = Qs & 7;
    const float* src = (dir ? wb : wf) + (size_t)(g * H_ + Q) * H_ + s * 16;
    _Float16* dst = wp + (size_t)idx * 16;
    #pragma unroll
    for (int k = 0; k < 16; ++k) dst[k] = (_Float16)src[k];
}

// ---------------------------------------------------------------------------
// K1: bf16 MFMA GEMM.  xp[dir][m][q*4+g] = x[m].w_ih[dir][g*128+q] + biases
// ---------------------------------------------------------------------------
__global__ __launch_bounds__(256) void gemm_in_mfma(
    const float* __restrict__ x,
    const float* __restrict__ w_f, const float* __restrict__ w_b,
    const float* __restrict__ bi_f, const float* __restrict__ bh_f,
    const float* __restrict__ bi_b, const float* __restrict__ bh_b,
    __hip_bfloat16* __restrict__ xp)
{
    const int nt  = blockIdx.x;          // 0..15
    const int m0  = blockIdx.y * 64;
    const int dir = nt >> 3;
    const int q0  = (nt & 7) * 16;
    const float* __restrict__ w  = dir ? w_b  : w_f;
    const float* __restrict__ bi = dir ? bi_b : bi_f;
    const float* __restrict__ bh = dir ? bh_b : bh_f;

    __shared__ alignas(16) unsigned short Asm[64 * 64];
    __shared__ alignas(16) unsigned short Bsm[64 * 64];
    __shared__ float bias_s[64];

    const int tid = threadIdx.x;
    const int wv  = tid >> 6;
    const int ln  = tid & 63;
    const int wr  = (wv >> 1) * 32;
    const int wc  = (wv & 1) * 32;
    const int l15 = ln & 15;
    const int l4  = ln >> 4;

#define STAGE_A(c2, k0) { int row = (c2) >> 3, kc = (c2) & 7; \
    const float4* sp = reinterpret_cast<const float4*>(x + (size_t)(m0 + row) * 256 + (k0) + kc * 8); \
    float4 fa = sp[0], fb = sp[1]; \
    u16x8 pk; pk[0]=f2bf(fa.x); pk[1]=f2bf(fa.y); pk[2]=f2bf(fa.z); pk[3]=f2bf(fa.w); \
    pk[4]=f2bf(fb.x); pk[5]=f2bf(fb.y); pk[6]=f2bf(fb.z); pk[7]=f2bf(fb.w); \
    *reinterpret_cast<u16x8*>(reinterpret_cast<char*>(Asm) + row * 128 + ((kc * 16) ^ ((row & 7) << 4))) = pk; }

#define STAGE_B(c2, k0) { int row = (c2) >> 3, kc = (c2) & 7; \
    int nglob = (row & 3) * 128 + q0 + (row >> 2); \
    const float4* sp = reinterpret_cast<const float4*>(w + (size_t)nglob * 256 + (k0) + kc * 8); \
    float4 fa = sp[0], fb = sp[1]; \
    u16x8 pk; pk[0]=f2bf(fa.x); pk[1]=f2bf(fa.y); pk[2]=f2bf(fa.z); pk[3]=f2bf(fa.w); \
    pk[4]=f2bf(fb.x); pk[5]=f2bf(fb.y); pk[6]=f2bf(fb.z); pk[7]=f2bf(fb.w); \
    *reinterpret_cast<u16x8*>(reinterpret_cast<char*>(Bsm) + row * 128 + ((kc * 16) ^ ((row & 7) << 4))) = pk; }

#define FRAG(BASE, rowe, kb) \
    __builtin_bit_cast(bf16x8, *reinterpret_cast<const uint4*>( \
        reinterpret_cast<const char*>(BASE) + (rowe) * 128 + ((kb) ^ (((rowe) & 7) << 4))))

    STAGE_A(tid, 0)  STAGE_A(tid + 256, 0)
    STAGE_B(tid, 0)  STAGE_B(tid + 256, 0)
    if (tid < 64) {
        int n = (tid & 3) * 128 + q0 + (tid >> 2);
        bias_s[tid] = bi[n] + bh[n];
    }
    __syncthreads();

    const float bv0 = bias_s[wc + l15];
    const float bv1 = bias_s[wc + 16 + l15];
    f32x4 acc00 = {bv0, bv0, bv0, bv0};
    f32x4 acc01 = {bv1, bv1, bv1, bv1};
    f32x4 acc10 = {bv0, bv0, bv0, bv0};
    f32x4 acc11 = {bv1, bv1, bv1, bv1};

    const int ra0 = wr + l15,      ra1 = wr + 16 + l15;
    const int rb0 = wc + l15,      rb1 = wc + 16 + l15;

    for (int kst = 0; kst < 4; ++kst) {
        if (kst) {
            __syncthreads();
            STAGE_A(tid, kst * 64)  STAGE_A(tid + 256, kst * 64)
            STAGE_B(tid, kst * 64)  STAGE_B(tid + 256, kst * 64)
            __syncthreads();
        }
        #pragma unroll
        for (int ks = 0; ks < 64; ks += 32) {
            int kb = ks * 2 + (l4 << 4);
            bf16x8 a0 = FRAG(Asm, ra0, kb);
            bf16x8 a1 = FRAG(Asm, ra1, kb);
            bf16x8 b0 = FRAG(Bsm, rb0, kb);
            bf16x8 b1 = FRAG(Bsm, rb1, kb);
            acc00 = __builtin_amdgcn_mfma_f32_16x16x32_bf16(a0, b0, acc00, 0, 0, 0);
            acc01 = __builtin_amdgcn_mfma_f32_16x16x32_bf16(a0, b1, acc01, 0, 0, 0);
            acc10 = __builtin_amdgcn_mfma_f32_16x16x32_bf16(a1, b0, acc10, 0, 0, 0);
            acc11 = __builtin_amdgcn_mfma_f32_16x16x32_bf16(a1, b1, acc11, 0, 0, 0);
        }
    }
    __syncthreads();

#define DWRITE(accv, mi, ni) { int row = wr + (mi) * 16 + l4 * 4; int col = wc + (ni) * 16 + l15; \
    Asm[(row + 0) * 64 + col] = f2bf(accv[0]); Asm[(row + 1) * 64 + col] = f2bf(accv[1]); \
    Asm[(row + 2) * 64 + col] = f2bf(accv[2]); Asm[(row + 3) * 64 + col] = f2bf(accv[3]); }
    DWRITE(acc00, 0, 0) DWRITE(acc01, 0, 1) DWRITE(acc10, 1, 0) DWRITE(acc11, 1, 1)
#undef DWRITE
    __syncthreads();

    #pragma unroll
    for (int p = 0; p < 2; ++p) {
        int c2 = tid + p * 256;
        int row = c2 >> 3, ch = c2 & 7;
        uint4 v = *reinterpret_cast<const uint4*>(reinterpret_cast<const char*>(Asm) + row * 128 + ch * 16);
        *reinterpret_cast<uint4*>(xp + ((size_t)dir * M_ + m0 + row) * G_ + q0 * 4 + ch * 8) = v;
    }
#undef STAGE_A
#undef STAGE_B
}

// ---------------------------------------------------------------------------
// K2 v3: r5 dot2 structure at 1024 threads for weight residency.
// 128 WGs = (dir, b); tid = Q*8 + s: lane owns all 4 gates of cell Q over
// K-chunk [s*16, s*16+16). W = 64 fp16 = 32 VGPRs (r12-proven residency
// point), loaded as 8 contiguous dwordx4 from the pre-converted wp.
// h-read: 32 B/lane broadcast (8 lanes/address; 2-way bank alias = free).
// Partial reduce over the 8 s-lanes entirely on the VALU pipe:
// xor1 (quad 0xB1) + xor2 (quad 0x4E) + xor7 (ROW_HALF_MIRROR 0x141).
// All lanes then hold all 4 gate sums -> redundant activation (r5 style).
// 4-step xp prefetch; one lgkm-only raw barrier per step.
// ---------------------------------------------------------------------------
__global__ __launch_bounds__(1024)
__attribute__((amdgpu_waves_per_eu(4, 4)))
void lstm_rec(
    const __hip_bfloat16* __restrict__ xp,   // [2][B][T][128][4]
    const _Float16* __restrict__ wp,         // [2][1024][64] per-lane order
    __hip_bfloat16* __restrict__ hs)         // [B][T][2H]
{
    const int wg  = blockIdx.x;
    const int dir = wg >> 6;
    const int b   = wg & 63;
    const int tid = threadIdx.x;   // 0..1023
    const int Q   = tid >> 3;
    const int s   = tid & 7;

    // ---- W: 64 fp16 contiguous = 8 x uint4 (32 VGPRs) --------------------
    const uint4* wq = reinterpret_cast<const uint4*>(
        wp + ((size_t)dir * 1024 + tid) * 64);
    uint4 W00 = wq[0], W01 = wq[1];   // gate i
    uint4 W10 = wq[2], W11 = wq[3];   // gate f
    uint4 W20 = wq[4], W21 = wq[5];   // gate g
    uint4 W30 = wq[6], W31 = wq[7];   // gate o

    __shared__ alignas(16) _Float16 hbuf[2][H_];
    if (tid < 2 * H_) (&hbuf[0][0])[tid] = (_Float16)0.f;
    float c = 0.f;
    __syncthreads();

    const unsigned short* __restrict__ xb =
        reinterpret_cast<const unsigned short*>(xp) + ((size_t)(dir * B_ + b)) * T_ * G_;
    __hip_bfloat16* __restrict__ ho =
        hs + (size_t)b * T_ * (2 * H_) + dir * H_ + Q;

    int t = dir ? (T_ - 1) : 0;
    const int dt = dir ? -1 : 1;

#define XPLD(sp) (*reinterpret_cast<const uint2*>( \
    xb + (size_t)(dir ? (T_ - 1 - (sp)) : (sp)) * G_ + Q * 4))
    uint2 cur0 = XPLD(0), cur1 = XPLD(1), cur2 = XPLD(2), cur3 = XPLD(3);

#define D8(WA, WB, P) { \
    P = dot2f(h2(WA.x), h2(u0.x), P); P = dot2f(h2(WA.y), h2(u0.y), P); \
    P = dot2f(h2(WA.z), h2(u0.z), P); P = dot2f(h2(WA.w), h2(u0.w), P); \
    P = dot2f(h2(WB.x), h2(u1.x), P); P = dot2f(h2(WB.y), h2(u1.y), P); \
    P = dot2f(h2(WB.z), h2(u1.z), P); P = dot2f(h2(WB.w), h2(u1.w), P); }

#define STEP(par, CUR) { \
    const _Float16* hp = hbuf[par] + s * 16; \
    uint4 u0 = *reinterpret_cast<const uint4*>(hp); \
    uint4 u1 = *reinterpret_cast<const uint4*>(hp + 8); \
    float p0 = 0.f, p1 = 0.f, p2 = 0.f, p3 = 0.f; \
    D8(W00, W01, p0)  D8(W10, W11, p1) \
    D8(W20, W21, p2)  D8(W30, W31, p3) \
    p0 += dpp_xor1(p0); p0 += dpp_xor2(p0); p0 += dpp_xor7(p0); \
    p1 += dpp_xor1(p1); p1 += dpp_xor2(p1); p1 += dpp_xor7(p1); \
    p2 += dpp_xor1(p2); p2 += dpp_xor2(p2); p2 += dpp_xor7(p2); \
    p3 += dpp_xor1(p3); p3 += dpp_xor2(p3); p3 += dpp_xor7(p3); \
    float xi = __uint_as_float(CUR.x << 16); \
    float xf = __uint_as_float(CUR.x & 0xffff0000u); \
    float xg = __uint_as_float(CUR.y << 16); \
    float xo = __uint_as_float(CUR.y & 0xffff0000u); \
    float si = sigp(p0 + xi), sf = sigp(p1 + xf); \
    float tg = tanhp(p2 + xg), so = sigp(p3 + xo); \
    c = fmaf(sf, c, si * tg); \
    float h = so * tanhp(c); \
    if (s == 0) { \
        hbuf[(par) ^ 1][Q] = (_Float16)h; \
        ho[(size_t)t * (2 * H_)] = __float2bfloat16(h); \
    } \
    asm volatile("s_waitcnt lgkmcnt(0)" ::: "memory"); \
    __builtin_amdgcn_s_barrier(); \
    t += dt; }

    for (int blk = 0; blk < T_ / 4; ++blk) {
        int base = blk * 4 + 4;
        int s0 = base     > T_ - 1 ? T_ - 1 : base;
        int s1 = base + 1 > T_ - 1 ? T_ - 1 : base + 1;
        int s2 = base + 2 > T_ - 1 ? T_ - 1 : base + 2;
        int s3 = base + 3 > T_ - 1 ? T_ - 1 : base + 3;
        uint2 nxt0 = XPLD(s0), nxt1 = XPLD(s1), nxt2 = XPLD(s2), nxt3 = XPLD(s3);

        STEP(0, cur0)
        STEP(1, cur1)
        STEP(0, cur2)
        STEP(1, cur3)

        cur0 = nxt0; cur1 = nxt1; cur2 = nxt2; cur3 = nxt3;
    }
#undef STEP
#undef D8
#undef XPLD
}

// ---------------------------------------------------------------------------
// K3: bf16 MFMA mixer. out[m][n] = hs[m].mixer_w[n] + mb[n], fp32 out.
// ---------------------------------------------------------------------------
__global__ __launch_bounds__(256) void mixer_mfma(
    const __hip_bfloat16* __restrict__ hs,   // [M][256] bf16
    const float* __restrict__ mw,            // [256][256] fp32
    const float* __restrict__ mb,
    float* __restrict__ out)                 // [M][256] fp32
{
    const int n0 = blockIdx.x * 64;
    const int m0 = blockIdx.y * 64;

    __shared__ alignas(16) unsigned short Asm[64 * 64];
    __shared__ alignas(16) unsigned short Bsm[64 * 64];
    __shared__ alignas(16) float Dlds[64 * 64];
    __shared__ float bias_s[64];

    const int tid = threadIdx.x;
    const int wv  = tid >> 6;
    const int ln  = tid & 63;
    const int wr  = (wv >> 1) * 32;
    const int wc  = (wv & 1) * 32;
    const int l15 = ln & 15;
    const int l4  = ln >> 4;

#define STAGE_A3(c2, k0) { int row = (c2) >> 3, kc = (c2) & 7; \
    uint4 v = *reinterpret_cast<const uint4*>(hs + (size_t)(m0 + row) * 256 + (k0) + kc * 8); \
    *reinterpret_cast<uint4*>(reinterpret_cast<char*>(Asm) + row * 128 + ((kc * 16) ^ ((row & 7) << 4))) = v; }
#define STAGE_B3(c2, k0) { int row = (c2) >> 3, kc = (c2) & 7; \
    const float4* sp = reinterpret_cast<const float4*>(mw + (size_t)(n0 + row) * 256 + (k0) + kc * 8); \
    float4 fa = sp[0], fb = sp[1]; \
    u16x8 pk; pk[0]=f2bf(fa.x); pk[1]=f2bf(fa.y); pk[2]=f2bf(fa.z); pk[3]=f2bf(fa.w); \
    pk[4]=f2bf(fb.x); pk[5]=f2bf(fb.y); pk[6]=f2bf(fb.z); pk[7]=f2bf(fb.w); \
    *reinterpret_cast<u16x8*>(reinterpret_cast<char*>(Bsm) + row * 128 + ((kc * 16) ^ ((row & 7) << 4))) = pk; }

#define FRAG(BASE, rowe, kb) \
    __builtin_bit_cast(bf16x8, *reinterpret_cast<const uint4*>( \
        reinterpret_cast<const char*>(BASE) + (rowe) * 128 + ((kb) ^ (((rowe) & 7) << 4))))

    STAGE_A3(tid, 0)  STAGE_A3(tid + 256, 0)
    STAGE_B3(tid, 0)  STAGE_B3(tid + 256, 0)
    if (tid < 64) bias_s[tid] = mb[n0 + tid];
    __syncthreads();

    const float bv0 = bias_s[wc + l15];
    const float bv1 = bias_s[wc + 16 + l15];
    f32x4 acc00 = {bv0, bv0, bv0, bv0};
    f32x4 acc01 = {bv1, bv1, bv1, bv1};
    f32x4 acc10 = {bv0, bv0, bv0, bv0};
    f32x4 acc11 = {bv1, bv1, bv1, bv1};

    const int ra0 = wr + l15,      ra1 = wr + 16 + l15;
    const int rb0 = wc + l15,      rb1 = wc + 16 + l15;

    for (int kst = 0; kst < 4; ++kst) {
        if (kst) {
            __syncthreads();
            STAGE_A3(tid, kst * 64)  STAGE_A3(tid + 256, kst * 64)
            STAGE_B3(tid, kst * 64)  STAGE_B3(tid + 256, kst * 64)
            __syncthreads();
        }
        #pragma unroll
        for (int ks = 0; ks < 64; ks += 32) {
            int kb = ks * 2 + (l4 << 4);
            bf16x8 a0 = FRAG(Asm, ra0, kb);
            bf16x8 a1 = FRAG(Asm, ra1, kb);
            bf16x8 b0 = FRAG(Bsm, rb0, kb);
            bf16x8 b1 = FRAG(Bsm, rb1, kb);
            acc00 = __builtin_amdgcn_mfma_f32_16x16x32_bf16(a0, b0, acc00, 0, 0, 0);
            acc01 = __builtin_amdgcn_mfma_f32_16x16x32_bf16(a0, b1, acc01, 0, 0, 0);
            acc10 = __builtin_amdgcn_mfma_f32_16x16x32_bf16(a1, b0, acc10, 0, 0, 0);
            acc11 = __builtin_amdgcn_mfma_f32_16x16x32_bf16(a1, b1, acc11, 0, 0, 0);
        }
    }
    __syncthreads();

#define DWRITE3(accv, mi, ni) { int row = wr + (mi) * 16 + l4 * 4; int col = wc + (ni) * 16 + l15; \
    Dlds[(row + 0) * 64 + col] = accv[0]; Dlds[(row + 1) * 64 + col] = accv[1]; \
    Dlds[(row + 2) * 64 + col] = accv[2]; Dlds[(row + 3) * 64 + col] = accv[3]; }
    DWRITE3(acc00, 0, 0) DWRITE3(acc01, 0, 1) DWRITE3(acc10, 1, 0) DWRITE3(acc11, 1, 1)
#undef DWRITE3
    __syncthreads();

    #pragma unroll
    for (int p = 0; p < 4; ++p) {
        int c2 = tid + p * 256;
        int row = c2 >> 4, ch = c2 & 15;
        float4 v = *reinterpret_cast<const float4*>(Dlds + row * 64 + ch * 4);
        *reinterpret_cast<float4*>(out + (size_t)(m0 + row) * 256 + n0 + ch * 4) = v;
    }
#undef STAGE_A3
#undef STAGE_B3
#undef FRAG
}

// ---------------------------------------------------------------------------
extern "C" void kernel_launch(void* const* d_in, const int* in_sizes, int n_in,
                              void* d_out, int out_size, void* d_ws, size_t ws_size,
                              hipStream_t stream) {
    const float* x       = (const float*)d_in[0];
    const float* w_ih_f  = (const float*)d_in[1];
    const float* w_hh_f  = (const float*)d_in[2];
    const float* b_ih_f  = (const float*)d_in[3];
    const float* b_hh_f  = (const float*)d_in[4];
    const float* w_ih_b  = (const float*)d_in[5];
    const float* w_hh_b  = (const float*)d_in[6];
    const float* b_ih_b  = (const float*)d_in[7];
    const float* b_hh_b  = (const float*)d_in[8];
    const float* mixer_w = (const float*)d_in[9];
    const float* mixer_b = (const float*)d_in[10];
    float* out = (float*)d_out;

    const size_t xp_bytes = (size_t)2 * M_ * G_ * sizeof(__hip_bfloat16); // 256 MiB
    const size_t hs_bytes = (size_t)M_ * 2 * H_ * sizeof(__hip_bfloat16); //  64 MiB
    const size_t wp_bytes = (size_t)2 * 1024 * 64 * sizeof(_Float16);     // 256 KiB
    if (ws_size < xp_bytes + hs_bytes + wp_bytes) return;

    __hip_bfloat16* xp = (__hip_bfloat16*)d_ws;
    __hip_bfloat16* hs = (__hip_bfloat16*)((char*)d_ws + xp_bytes);
    _Float16*       wpb = (_Float16*)((char*)d_ws + xp_bytes + hs_bytes);

    conv_whh<<<32, 256, 0, stream>>>(w_hh_f, w_hh_b, wpb);
    gemm_in_mfma<<<dim3(16, M_ / 64), 256, 0, stream>>>(
        x, w_ih_f, w_ih_b, b_ih_f, b_hh_f, b_ih_b, b_hh_b, xp);
    lstm_rec<<<128, 1024, 0, stream>>>(xp, wpb, hs);
    mixer_mfma<<<dim3(4, M_ / 64), 256, 0, stream>>>(
        hs, mixer_w, mixer_b, out);
}

// Round 14
// 1862.853 us; speedup vs baseline: 1.6094x; 1.0634x over previous
//
#include <hip/hip_runtime.h>
#include <hip/hip_bf16.h>

#define B_   64
#define T_   2048
#define IN_  256
#define H_   128
#define G_   512          // 4*H
#define M_   (B_ * T_)    // 131072

typedef __bf16 bf16x8 __attribute__((ext_vector_type(8)));
typedef _Float16 f16x8 __attribute__((ext_vector_type(8)));
typedef float f32x4 __attribute__((ext_vector_type(4)));
typedef unsigned short u16x8 __attribute__((ext_vector_type(8)));

#define L2E_  1.442695041f

__device__ __forceinline__ unsigned short f2bf(float f) {   // RNE fp32->bf16
    unsigned u = __float_as_uint(f);
    return (unsigned short)((u + 0x7fffu + ((u >> 16) & 1u)) >> 16);
}
__device__ __forceinline__ float sigp(float x) {
    return __builtin_amdgcn_rcpf(1.f + __builtin_amdgcn_exp2f(-L2E_ * x));
}
__device__ __forceinline__ float tanhp(float x) {
    return fmaf(2.f, __builtin_amdgcn_rcpf(1.f + __builtin_amdgcn_exp2f(-2.f * L2E_ * x)), -1.f);
}
__device__ __forceinline__ f16x8 F8(uint4 u) {
    return __builtin_bit_cast(f16x8, u);
}

// ---------------------------------------------------------------------------
// K0: pre-pack w_hh (fp32) -> wp2 (fp16) in K2's exact A-fragment order.
// Frag index f = ts*4 + kt.  Lane (w,l): A-frag value i of frag f is
// W'[32w + 16ts + (l&15)][32kt + 8*(l>>4) + i], with W'[r] = w_hh[(r&3)*128+(r>>2)].
// wp2 layout: [((dir*16 + w)*64 + l)*8 + f][8 halfs]  -> 128 B contiguous/lane.
// ---------------------------------------------------------------------------
__global__ __launch_bounds__(256) void conv_whh2(
    const float* __restrict__ wf, const float* __restrict__ wb,
    _Float16* __restrict__ wp)
{
    int idx = blockIdx.x * 256 + threadIdx.x;   // 0..16383 = (dir,w,l,f)
    int f   = idx & 7;
    int l   = (idx >> 3) & 63;
    int w   = (idx >> 9) & 15;
    int dir = idx >> 13;
    int ts = f >> 2, kt = f & 3;
    int l15 = l & 15, l4 = l >> 4;
    int r = 32 * w + 16 * ts + l15;
    int g = r & 3, Q = r >> 2;
    const float* src = (dir ? wb : wf) + (size_t)(g * H_ + Q) * H_ + 32 * kt + 8 * l4;
    _Float16* dst = wp + (size_t)idx * 8;
    #pragma unroll
    for (int i = 0; i < 8; ++i) dst[i] = (_Float16)src[i];
}

// ---------------------------------------------------------------------------
// K1: bf16 MFMA GEMM.  xp[dir][m][q*4+g] = x[m].w_ih[dir][g*128+q] + biases
// ---------------------------------------------------------------------------
__global__ __launch_bounds__(256) void gemm_in_mfma(
    const float* __restrict__ x,
    const float* __restrict__ w_f, const float* __restrict__ w_b,
    const float* __restrict__ bi_f, const float* __restrict__ bh_f,
    const float* __restrict__ bi_b, const float* __restrict__ bh_b,
    __hip_bfloat16* __restrict__ xp)
{
    const int nt  = blockIdx.x;          // 0..15
    const int m0  = blockIdx.y * 64;
    const int dir = nt >> 3;
    const int q0  = (nt & 7) * 16;
    const float* __restrict__ w  = dir ? w_b  : w_f;
    const float* __restrict__ bi = dir ? bi_b : bi_f;
    const float* __restrict__ bh = dir ? bh_b : bh_f;

    __shared__ alignas(16) unsigned short Asm[64 * 64];
    __shared__ alignas(16) unsigned short Bsm[64 * 64];
    __shared__ float bias_s[64];

    const int tid = threadIdx.x;
    const int wv  = tid >> 6;
    const int ln  = tid & 63;
    const int wr  = (wv >> 1) * 32;
    const int wc  = (wv & 1) * 32;
    const int l15 = ln & 15;
    const int l4  = ln >> 4;

#define STAGE_A(c2, k0) { int row = (c2) >> 3, kc = (c2) & 7; \
    const float4* sp = reinterpret_cast<const float4*>(x + (size_t)(m0 + row) * 256 + (k0) + kc * 8); \
    float4 fa = sp[0], fb = sp[1]; \
    u16x8 pk; pk[0]=f2bf(fa.x); pk[1]=f2bf(fa.y); pk[2]=f2bf(fa.z); pk[3]=f2bf(fa.w); \
    pk[4]=f2bf(fb.x); pk[5]=f2bf(fb.y); pk[6]=f2bf(fb.z); pk[7]=f2bf(fb.w); \
    *reinterpret_cast<u16x8*>(reinterpret_cast<char*>(Asm) + row * 128 + ((kc * 16) ^ ((row & 7) << 4))) = pk; }

#define STAGE_B(c2, k0) { int row = (c2) >> 3, kc = (c2) & 7; \
    int nglob = (row & 3) * 128 + q0 + (row >> 2); \
    const float4* sp = reinterpret_cast<const float4*>(w + (size_t)nglob * 256 + (k0) + kc * 8); \
    float4 fa = sp[0], fb = sp[1]; \
    u16x8 pk; pk[0]=f2bf(fa.x); pk[1]=f2bf(fa.y); pk[2]=f2bf(fa.z); pk[3]=f2bf(fa.w); \
    pk[4]=f2bf(fb.x); pk[5]=f2bf(fb.y); pk[6]=f2bf(fb.z); pk[7]=f2bf(fb.w); \
    *reinterpret_cast<u16x8*>(reinterpret_cast<char*>(Bsm) + row * 128 + ((kc * 16) ^ ((row & 7) << 4))) = pk; }

#define FRAG(BASE, rowe, kb) \
    __builtin_bit_cast(bf16x8, *reinterpret_cast<const uint4*>( \
        reinterpret_cast<const char*>(BASE) + (rowe) * 128 + ((kb) ^ (((rowe) & 7) << 4))))

    STAGE_A(tid, 0)  STAGE_A(tid + 256, 0)
    STAGE_B(tid, 0)  STAGE_B(tid + 256, 0)
    if (tid < 64) {
        int n = (tid & 3) * 128 + q0 + (tid >> 2);
        bias_s[tid] = bi[n] + bh[n];
    }
    __syncthreads();

    const float bv0 = bias_s[wc + l15];
    const float bv1 = bias_s[wc + 16 + l15];
    f32x4 acc00 = {bv0, bv0, bv0, bv0};
    f32x4 acc01 = {bv1, bv1, bv1, bv1};
    f32x4 acc10 = {bv0, bv0, bv0, bv0};
    f32x4 acc11 = {bv1, bv1, bv1, bv1};

    const int ra0 = wr + l15,      ra1 = wr + 16 + l15;
    const int rb0 = wc + l15,      rb1 = wc + 16 + l15;

    for (int kst = 0; kst < 4; ++kst) {
        if (kst) {
            __syncthreads();
            STAGE_A(tid, kst * 64)  STAGE_A(tid + 256, kst * 64)
            STAGE_B(tid, kst * 64)  STAGE_B(tid + 256, kst * 64)
            __syncthreads();
        }
        #pragma unroll
        for (int ks = 0; ks < 64; ks += 32) {
            int kb = ks * 2 + (l4 << 4);
            bf16x8 a0 = FRAG(Asm, ra0, kb);
            bf16x8 a1 = FRAG(Asm, ra1, kb);
            bf16x8 b0 = FRAG(Bsm, rb0, kb);
            bf16x8 b1 = FRAG(Bsm, rb1, kb);
            acc00 = __builtin_amdgcn_mfma_f32_16x16x32_bf16(a0, b0, acc00, 0, 0, 0);
            acc01 = __builtin_amdgcn_mfma_f32_16x16x32_bf16(a0, b1, acc01, 0, 0, 0);
            acc10 = __builtin_amdgcn_mfma_f32_16x16x32_bf16(a1, b0, acc10, 0, 0, 0);
            acc11 = __builtin_amdgcn_mfma_f32_16x16x32_bf16(a1, b1, acc11, 0, 0, 0);
        }
    }
    __syncthreads();

#define DWRITE(accv, mi, ni) { int row = wr + (mi) * 16 + l4 * 4; int col = wc + (ni) * 16 + l15; \
    Asm[(row + 0) * 64 + col] = f2bf(accv[0]); Asm[(row + 1) * 64 + col] = f2bf(accv[1]); \
    Asm[(row + 2) * 64 + col] = f2bf(accv[2]); Asm[(row + 3) * 64 + col] = f2bf(accv[3]); }
    DWRITE(acc00, 0, 0) DWRITE(acc01, 0, 1) DWRITE(acc10, 1, 0) DWRITE(acc11, 1, 1)
#undef DWRITE
    __syncthreads();

    #pragma unroll
    for (int p = 0; p < 2; ++p) {
        int c2 = tid + p * 256;
        int row = c2 >> 3, ch = c2 & 7;
        uint4 v = *reinterpret_cast<const uint4*>(reinterpret_cast<const char*>(Asm) + row * 128 + ch * 16);
        *reinterpret_cast<uint4*>(xp + ((size_t)dir * M_ + m0 + row) * G_ + q0 * 4 + ch * 8) = v;
    }
#undef STAGE_A
#undef STAGE_B
}

// ---------------------------------------------------------------------------
// K2 v4: MFMA recurrence at the 32-reg residency point.
// 128 WGs = (dir, b); 1024 thr = 16 waves. Wave w owns W' row-tiles
// {2w, 2w+1} -> 8 A-frags = 32 VGPRs (r12/r13-proven resident), loaded as
// 8 contiguous dwordx4 from pre-packed wp2 (no convert chain to remat).
// B = h broadcast to all 16 cols (4 distinct LDS addrs/wave = broadcast).
// 8 MFMA/wave/step on the (idle) matrix pipe. D reg j = gate j of cell
// 8w+l4 (a0) / 8w+4+l4 (a1); lanes l15<8 activate cell A, l15>=8 cell B
// (1 cell = 10 trans/lane); writers l15 in {0,8}. acc init from 4-step
// prefetched xp (input+bias). One lgkm-only raw barrier per step.
// ---------------------------------------------------------------------------
__global__ __launch_bounds__(1024)
__attribute__((amdgpu_waves_per_eu(4, 4)))
void lstm_rec(
    const __hip_bfloat16* __restrict__ xp,   // [2][B][T][128][4]
    const _Float16* __restrict__ wp,         // [2][16][64][8][8] frag order
    __hip_bfloat16* __restrict__ hs)         // [B][T][2H]
{
    const int wg  = blockIdx.x;
    const int dir = wg >> 6;
    const int b   = wg & 63;
    const int tid = threadIdx.x;
    const int w   = tid >> 6;
    const int l   = tid & 63;
    const int l15 = l & 15;
    const int l4  = l >> 4;
    const bool selA = (l15 < 8);

    // ---- W A-fragments: 8 x uint4 = 32 VGPRs, contiguous 128 B -----------
    const uint4* wq = reinterpret_cast<const uint4*>(
        wp + ((size_t)((dir * 16 + w) * 64 + l)) * 64);
    uint4 W00 = wq[0], W01 = wq[1], W02 = wq[2], W03 = wq[3];  // ts=0, kt=0..3
    uint4 W10 = wq[4], W11 = wq[5], W12 = wq[6], W13 = wq[7];  // ts=1

    __shared__ alignas(16) _Float16 hbuf[2][H_];
    if (tid < 2 * H_) (&hbuf[0][0])[tid] = (_Float16)0.f;
    __syncthreads();

    const unsigned short* __restrict__ xb =
        reinterpret_cast<const unsigned short*>(xp) + ((size_t)(dir * B_ + b)) * T_ * G_;
    const int QA = 8 * w + l4;
    const int QB = QA + 4;
    const int Qw = selA ? QA : QB;          // cell this lane activates
    __hip_bfloat16* __restrict__ ho =
        hs + (size_t)b * T_ * (2 * H_) + dir * H_ + Qw;
    const bool writer = (l15 == 0) || (l15 == 8);

    float c = 0.f;
    int t = dir ? (T_ - 1) : 0;
    const int dt = dir ? -1 : 1;

    const int xoffA = 4 * QA;
    const int xoffB = 4 * QB;

#define XPLD(sp, off) (*reinterpret_cast<const uint2*>( \
    xb + (size_t)(dir ? (T_ - 1 - (sp)) : (sp)) * G_ + (off)))

    uint2 cA0 = XPLD(0, xoffA), cA1 = XPLD(0, xoffB);
    uint2 cB0 = XPLD(1, xoffA), cB1 = XPLD(1, xoffB);
    uint2 cC0 = XPLD(2, xoffA), cC1 = XPLD(2, xoffB);
    uint2 cD0 = XPLD(3, xoffA), cD1 = XPLD(3, xoffB);

#define LOF(u) __uint_as_float((u) << 16)
#define HIF(u) __uint_as_float((u) & 0xffff0000u)
#define MFMA16(A, B, C) __builtin_amdgcn_mfma_f32_16x16x32_f16(A, B, C, 0, 0, 0)

#define STEP(par, XA, XB) { \
    const char* hp = reinterpret_cast<const char*>(&hbuf[par][0]) + l4 * 16; \
    f16x8 hb0 = *reinterpret_cast<const f16x8*>(hp + 0); \
    f16x8 hb1 = *reinterpret_cast<const f16x8*>(hp + 64); \
    f16x8 hb2 = *reinterpret_cast<const f16x8*>(hp + 128); \
    f16x8 hb3 = *reinterpret_cast<const f16x8*>(hp + 192); \
    f32x4 a0, a1; \
    a0[0] = LOF(XA.x); a0[1] = HIF(XA.x); a0[2] = LOF(XA.y); a0[3] = HIF(XA.y); \
    a1[0] = LOF(XB.x); a1[1] = HIF(XB.x); a1[2] = LOF(XB.y); a1[3] = HIF(XB.y); \
    a0 = MFMA16(F8(W00), hb0, a0); a1 = MFMA16(F8(W10), hb0, a1); \
    a0 = MFMA16(F8(W01), hb1, a0); a1 = MFMA16(F8(W11), hb1, a1); \
    a0 = MFMA16(F8(W02), hb2, a0); a1 = MFMA16(F8(W12), hb2, a1); \
    a0 = MFMA16(F8(W03), hb3, a0); a1 = MFMA16(F8(W13), hb3, a1); \
    float gi = selA ? a0[0] : a1[0]; \
    float gf = selA ? a0[1] : a1[1]; \
    float gg = selA ? a0[2] : a1[2]; \
    float go = selA ? a0[3] : a1[3]; \
    float si = sigp(gi), sf = sigp(gf); \
    float tg = tanhp(gg), so = sigp(go); \
    c = fmaf(sf, c, si * tg); \
    float h = so * tanhp(c); \
    if (writer) { \
        hbuf[(par) ^ 1][Qw] = (_Float16)h; \
        ho[(size_t)t * (2 * H_)] = __float2bfloat16(h); \
    } \
    asm volatile("s_waitcnt lgkmcnt(0)" ::: "memory"); \
    __builtin_amdgcn_s_barrier(); \
    t += dt; }

    for (int blk = 0; blk < T_ / 4; ++blk) {
        int base = blk * 4 + 4;
        int s0 = base     > T_ - 1 ? T_ - 1 : base;
        int s1 = base + 1 > T_ - 1 ? T_ - 1 : base + 1;
        int s2 = base + 2 > T_ - 1 ? T_ - 1 : base + 2;
        int s3 = base + 3 > T_ - 1 ? T_ - 1 : base + 3;
        uint2 nA0 = XPLD(s0, xoffA), nA1 = XPLD(s0, xoffB);
        uint2 nB0 = XPLD(s1, xoffA), nB1 = XPLD(s1, xoffB);
        uint2 nC0 = XPLD(s2, xoffA), nC1 = XPLD(s2, xoffB);
        uint2 nD0 = XPLD(s3, xoffA), nD1 = XPLD(s3, xoffB);

        STEP(0, cA0, cA1)
        STEP(1, cB0, cB1)
        STEP(0, cC0, cC1)
        STEP(1, cD0, cD1)

        cA0 = nA0; cA1 = nA1; cB0 = nB0; cB1 = nB1;
        cC0 = nC0; cC1 = nC1; cD0 = nD0; cD1 = nD1;
    }
#undef STEP
#undef MFMA16
#undef LOF
#undef HIF
#undef XPLD
}

// ---------------------------------------------------------------------------
// K3: bf16 MFMA mixer. out[m][n] = hs[m].mixer_w[n] + mb[n], fp32 out.
// ---------------------------------------------------------------------------
__global__ __launch_bounds__(256) void mixer_mfma(
    const __hip_bfloat16* __restrict__ hs,   // [M][256] bf16
    const float* __restrict__ mw,            // [256][256] fp32
    const float* __restrict__ mb,
    float* __restrict__ out)                 // [M][256] fp32
{
    const int n0 = blockIdx.x * 64;
    const int m0 = blockIdx.y * 64;

    __shared__ alignas(16) unsigned short Asm[64 * 64];
    __shared__ alignas(16) unsigned short Bsm[64 * 64];
    __shared__ alignas(16) float Dlds[64 * 64];
    __shared__ float bias_s[64];

    const int tid = threadIdx.x;
    const int wv  = tid >> 6;
    const int ln  = tid & 63;
    const int wr  = (wv >> 1) * 32;
    const int wc  = (wv & 1) * 32;
    const int l15 = ln & 15;
    const int l4  = ln >> 4;

#define STAGE_A3(c2, k0) { int row = (c2) >> 3, kc = (c2) & 7; \
    uint4 v = *reinterpret_cast<const uint4*>(hs + (size_t)(m0 + row) * 256 + (k0) + kc * 8); \
    *reinterpret_cast<uint4*>(reinterpret_cast<char*>(Asm) + row * 128 + ((kc * 16) ^ ((row & 7) << 4))) = v; }
#define STAGE_B3(c2, k0) { int row = (c2) >> 3, kc = (c2) & 7; \
    const float4* sp = reinterpret_cast<const float4*>(mw + (size_t)(n0 + row) * 256 + (k0) + kc * 8); \
    float4 fa = sp[0], fb = sp[1]; \
    u16x8 pk; pk[0]=f2bf(fa.x); pk[1]=f2bf(fa.y); pk[2]=f2bf(fa.z); pk[3]=f2bf(fa.w); \
    pk[4]=f2bf(fb.x); pk[5]=f2bf(fb.y); pk[6]=f2bf(fb.z); pk[7]=f2bf(fb.w); \
    *reinterpret_cast<u16x8*>(reinterpret_cast<char*>(Bsm) + row * 128 + ((kc * 16) ^ ((row & 7) << 4))) = pk; }

#define FRAG(BASE, rowe, kb) \
    __builtin_bit_cast(bf16x8, *reinterpret_cast<const uint4*>( \
        reinterpret_cast<const char*>(BASE) + (rowe) * 128 + ((kb) ^ (((rowe) & 7) << 4))))

    STAGE_A3(tid, 0)  STAGE_A3(tid + 256, 0)
    STAGE_B3(tid, 0)  STAGE_B3(tid + 256, 0)
    if (tid < 64) bias_s[tid] = mb[n0 + tid];
    __syncthreads();

    const float bv0 = bias_s[wc + l15];
    const float bv1 = bias_s[wc + 16 + l15];
    f32x4 acc00 = {bv0, bv0, bv0, bv0};
    f32x4 acc01 = {bv1, bv1, bv1, bv1};
    f32x4 acc10 = {bv0, bv0, bv0, bv0};
    f32x4 acc11 = {bv1, bv1, bv1, bv1};

    const int ra0 = wr + l15,      ra1 = wr + 16 + l15;
    const int rb0 = wc + l15,      rb1 = wc + 16 + l15;

    for (int kst = 0; kst < 4; ++kst) {
        if (kst) {
            __syncthreads();
            STAGE_A3(tid, kst * 64)  STAGE_A3(tid + 256, kst * 64)
            STAGE_B3(tid, kst * 64)  STAGE_B3(tid + 256, kst * 64)
            __syncthreads();
        }
        #pragma unroll
        for (int ks = 0; ks < 64; ks += 32) {
            int kb = ks * 2 + (l4 << 4);
            bf16x8 a0 = FRAG(Asm, ra0, kb);
            bf16x8 a1 = FRAG(Asm, ra1, kb);
            bf16x8 b0 = FRAG(Bsm, rb0, kb);
            bf16x8 b1 = FRAG(Bsm, rb1, kb);
            acc00 = __builtin_amdgcn_mfma_f32_16x16x32_bf16(a0, b0, acc00, 0, 0, 0);
            acc01 = __builtin_amdgcn_mfma_f32_16x16x32_bf16(a0, b1, acc01, 0, 0, 0);
            acc10 = __builtin_amdgcn_mfma_f32_16x16x32_bf16(a1, b0, acc10, 0, 0, 0);
            acc11 = __builtin_amdgcn_mfma_f32_16x16x32_bf16(a1, b1, acc11, 0, 0, 0);
        }
    }
    __syncthreads();

#define DWRITE3(accv, mi, ni) { int row = wr + (mi) * 16 + l4 * 4; int col = wc + (ni) * 16 + l15; \
    Dlds[(row + 0) * 64 + col] = accv[0]; Dlds[(row + 1) * 64 + col] = accv[1]; \
    Dlds[(row + 2) * 64 + col] = accv[2]; Dlds[(row + 3) * 64 + col] = accv[3]; }
    DWRITE3(acc00, 0, 0) DWRITE3(acc01, 0, 1) DWRITE3(acc10, 1, 0) DWRITE3(acc11, 1, 1)
#undef DWRITE3
    __syncthreads();

    #pragma unroll
    for (int p = 0; p < 4; ++p) {
        int c2 = tid + p * 256;
        int row = c2 >> 4, ch = c2 & 15;
        float4 v = *reinterpret_cast<const float4*>(Dlds + row * 64 + ch * 4);
        *reinterpret_cast<float4*>(out + (size_t)(m0 + row) * 256 + n0 + ch * 4) = v;
    }
#undef STAGE_A3
#undef STAGE_B3
#undef FRAG
}

// ---------------------------------------------------------------------------
extern "C" void kernel_launch(void* const* d_in, const int* in_sizes, int n_in,
                              void* d_out, int out_size, void* d_ws, size_t ws_size,
                              hipStream_t stream) {
    const float* x       = (const float*)d_in[0];
    const float* w_ih_f  = (const float*)d_in[1];
    const float* w_hh_f  = (const float*)d_in[2];
    const float* b_ih_f  = (const float*)d_in[3];
    const float* b_hh_f  = (const float*)d_in[4];
    const float* w_ih_b  = (const float*)d_in[5];
    const float* w_hh_b  = (const float*)d_in[6];
    const float* b_ih_b  = (const float*)d_in[7];
    const float* b_hh_b  = (const float*)d_in[8];
    const float* mixer_w = (const float*)d_in[9];
    const float* mixer_b = (const float*)d_in[10];
    float* out = (float*)d_out;

    const size_t xp_bytes = (size_t)2 * M_ * G_ * sizeof(__hip_bfloat16); // 256 MiB
    const size_t hs_bytes = (size_t)M_ * 2 * H_ * sizeof(__hip_bfloat16); //  64 MiB
    const size_t wp_bytes = (size_t)16384 * 8 * sizeof(_Float16);         // 256 KiB
    if (ws_size < xp_bytes + hs_bytes + wp_bytes) return;

    __hip_bfloat16* xp = (__hip_bfloat16*)d_ws;
    __hip_bfloat16* hs = (__hip_bfloat16*)((char*)d_ws + xp_bytes);
    _Float16*       wpb = (_Float16*)((char*)d_ws + xp_bytes + hs_bytes);

    conv_whh2<<<64, 256, 0, stream>>>(w_hh_f, w_hh_b, wpb);
    gemm_in_mfma<<<dim3(16, M_ / 64), 256, 0, stream>>>(
        x, w_ih_f, w_ih_b, b_ih_f, b_hh_f, b_ih_b, b_hh_b, xp);
    lstm_rec<<<128, 1024, 0, stream>>>(xp, wpb, hs);
    mixer_mfma<<<dim3(4, M_ / 64), 256, 0, stream>>>(
        hs, mixer_w, mixer_b, out);
}